// Round 5
// baseline (300.550 us; speedup 1.0000x reference)
//
#include <hip/hip_runtime.h>
#include <math.h>

#define BATCH 16384
#define DM    2048
#define NE    64
#define BT    32
#define DK    32
#define NBLK  (BATCH / BT)   // 512

// out layout (floats): idx @0 (32768), w @32768 (32768), logits @65536 (1048576), aux @1114112
#define OFF_W   32768
#define OFF_LG  65536
#define OFF_AUX 1114112

// ws layout (floats): probs partial [NBLK][64] @0, usage partial [NBLK][64] @32768. 256 KiB total.
#define WS_USAGE (NBLK * NE)

__global__ __launch_bounds__(256) void router_kernel(
    const float* __restrict__ H, const float* __restrict__ W,
    const float* __restrict__ NZ, float* __restrict__ out,
    float* __restrict__ ws)
{
    // GEMM staging (separate from epilogue smem — no aliasing anywhere)
    __shared__ float hs [DK * 36];   // [d][t], 32x36 (pad)
    __shared__ float wsm[DK * 68];   // [d][e], 32x68 (pad)
    __shared__ float ps [16 * 68];   // [tr][e] prob partials
    __shared__ int   cnt[NE];        // usage counts (int atomics: exact, order-free)

    const int tid = threadIdx.x;
    const int blk = blockIdx.x;
    const int er  = tid & 15;        // expert group -> experts e4..e4+3
    const int tr  = tid >> 4;        // token group  -> tokens t2, t2+1
    const int e4  = er << 2;
    const int t2  = tr << 1;
    // NOTE: lanes of one token group = (tr&3)*16 + er -> 16 CONSECUTIVE lanes of one wave,
    // so __shfl_xor with mask<16 stays inside the group.

    float a00=0,a01=0,a02=0,a03=0, a10=0,a11=0,a12=0,a13=0;

    const float* hb = H + (size_t)blk * BT * DM;
    const int ht = tid >> 3;         // 0..31 (token row to stage)
    const int hd = (tid & 7) << 2;   // 0..28

    for (int d0 = 0; d0 < DM; d0 += DK) {
        // issue all global loads first
        float4 hv = *(const float4*)(hb + (size_t)ht * DM + d0 + hd);
        float4 w0 = *(const float4*)(W  + (size_t)ht        * DM + d0 + hd);
        float4 w1 = *(const float4*)(W  + (size_t)(ht + 32) * DM + d0 + hd);
        // transpose into LDS [d][row]
        hs[(hd+0)*36 + ht] = hv.x;
        hs[(hd+1)*36 + ht] = hv.y;
        hs[(hd+2)*36 + ht] = hv.z;
        hs[(hd+3)*36 + ht] = hv.w;
        wsm[(hd+0)*68 + ht] = w0.x;
        wsm[(hd+1)*68 + ht] = w0.y;
        wsm[(hd+2)*68 + ht] = w0.z;
        wsm[(hd+3)*68 + ht] = w0.w;
        wsm[(hd+0)*68 + ht+32] = w1.x;
        wsm[(hd+1)*68 + ht+32] = w1.y;
        wsm[(hd+2)*68 + ht+32] = w1.z;
        wsm[(hd+3)*68 + ht+32] = w1.w;
        __syncthreads();
        #pragma unroll
        for (int dd = 0; dd < DK; ++dd) {
            const float2 av = *(const float2*)(hs  + dd*36 + t2);
            const float4 bv = *(const float4*)(wsm + dd*68 + e4);
            a00 += av.x*bv.x; a01 += av.x*bv.y; a02 += av.x*bv.z; a03 += av.x*bv.w;
            a10 += av.y*bv.x; a11 += av.y*bv.y; a12 += av.y*bv.z; a13 += av.y*bv.w;
        }
        __syncthreads();
    }

    // ---- epilogue: all register/shuffle, no reuse of GEMM smem ----
    float l[2][4];
    {
        size_t tg0 = (size_t)blk * BT + t2;
        float4 n0 = *(const float4*)(NZ + tg0 * NE + e4);
        float4 n1 = *(const float4*)(NZ + (tg0 + 1) * NE + e4);
        l[0][0] = a00 + n0.x*0.1f; l[0][1] = a01 + n0.y*0.1f;
        l[0][2] = a02 + n0.z*0.1f; l[0][3] = a03 + n0.w*0.1f;
        l[1][0] = a10 + n1.x*0.1f; l[1][1] = a11 + n1.y*0.1f;
        l[1][2] = a12 + n1.z*0.1f; l[1][3] = a13 + n1.w*0.1f;
        *(float4*)(out + OFF_LG + tg0 * NE + e4)       = make_float4(l[0][0],l[0][1],l[0][2],l[0][3]);
        *(float4*)(out + OFF_LG + (tg0 + 1) * NE + e4) = make_float4(l[1][0],l[1][1],l[1][2],l[1][3]);
    }
    if (tid < NE) cnt[tid] = 0;
    __syncthreads();

    float pe0 = 0.f, pe1 = 0.f, pe2 = 0.f, pe3 = 0.f;
    #pragma unroll
    for (int i = 0; i < 2; ++i) {
        // local top-2 over this lane's 4 experts (stable: lower index wins ties)
        float m1 = l[i][0]; int i1 = e4;
        float m2 = -INFINITY; int i2 = NE;
        #pragma unroll
        for (int j = 1; j < 4; ++j) {
            float v = l[i][j]; int e = e4 + j;
            if (v > m1) { m2 = m1; i2 = i1; m1 = v; i1 = e; }
            else if (v > m2) { m2 = v; i2 = e; }
        }
        // butterfly merge across the 16 lanes of this token group
        #pragma unroll
        for (int mask = 1; mask < 16; mask <<= 1) {
            float om1 = __shfl_xor(m1, mask);
            int   oi1 = __shfl_xor(i1, mask);
            float om2 = __shfl_xor(m2, mask);
            int   oi2 = __shfl_xor(i2, mask);
            bool oFirst = (om1 > m1) || (om1 == m1 && oi1 < i1);
            if (oFirst) {
                bool selfSecond = (m1 > om2) || (m1 == om2 && i1 < oi2);
                m2 = selfSecond ? m1 : om2;
                i2 = selfSecond ? i1 : oi2;
                m1 = om1; i1 = oi1;
            } else {
                bool otherSecond = (om1 > m2) || (om1 == m2 && oi1 < i2);
                if (otherSecond) { m2 = om1; i2 = oi1; }
            }
        }
        // full-row softmax denom (m1 is the exact row max)
        float p0 = expf(l[i][0] - m1);
        float p1 = expf(l[i][1] - m1);
        float p2 = expf(l[i][2] - m1);
        float p3 = expf(l[i][3] - m1);
        float s = p0 + p1 + p2 + p3;
        #pragma unroll
        for (int mask = 1; mask < 16; mask <<= 1) s += __shfl_xor(s, mask);
        float inv = 1.0f / s;
        pe0 += p0*inv; pe1 += p1*inv; pe2 += p2*inv; pe3 += p3*inv;
        if (er == 0) {
            size_t tg = (size_t)blk * BT + t2 + i;
            out[tg*2 + 0] = (float)i1;
            out[tg*2 + 1] = (float)i2;
            float x  = expf(m2 - m1);
            float w1v = 1.0f / (1.0f + x);
            out[OFF_W + tg*2 + 0] = w1v;
            out[OFF_W + tg*2 + 1] = x * w1v;
            atomicAdd(&cnt[i1], 1);
            atomicAdd(&cnt[i2], 1);
        }
    }
    ps[tr*68 + e4 + 0] = pe0;
    ps[tr*68 + e4 + 1] = pe1;
    ps[tr*68 + e4 + 2] = pe2;
    ps[tr*68 + e4 + 3] = pe3;
    __syncthreads();

    if (tid < NE) {
        float s = 0.f;
        #pragma unroll
        for (int r = 0; r < 16; ++r) s += ps[r*68 + tid];
        ws[(size_t)blk * NE + tid] = s;                       // prob partial
        ws[WS_USAGE + (size_t)blk * NE + tid] = (float)cnt[tid]; // usage partial
    }
}

__global__ __launch_bounds__(256) void finalize_kernel(
    const float* __restrict__ ws, float* __restrict__ out)
{
    __shared__ float psum[256];
    __shared__ float usum[256];
    const int tid  = threadIdx.x;
    const int e    = tid & 63;
    const int part = tid >> 6;   // 0..3, each covers 128 blocks in fixed order
    float p = 0.f, u = 0.f;
    for (int b = part * 128; b < part * 128 + 128; ++b) {
        p += ws[(size_t)b * NE + e];
        u += ws[WS_USAGE + (size_t)b * NE + e];
    }
    psum[part*64 + e] = p;
    usum[part*64 + e] = u;
    __syncthreads();
    if (tid < 64) {
        float pv = psum[tid] + psum[64+tid] + psum[128+tid] + psum[192+tid];
        float uv = usum[tid] + usum[64+tid] + usum[128+tid] + usum[192+tid];
        float v = (uv / (float)(BATCH * 2)) * (pv / (float)BATCH);
        #pragma unroll
        for (int mask = 1; mask < 64; mask <<= 1) v += __shfl_xor(v, mask);
        if (tid == 0) out[OFF_AUX] = v * ((float)NE * 0.001f);
    }
}

extern "C" void kernel_launch(void* const* d_in, const int* in_sizes, int n_in,
                              void* d_out, int out_size, void* d_ws, size_t ws_size,
                              hipStream_t stream)
{
    const float* H  = (const float*)d_in[0];
    const float* W  = (const float*)d_in[1];
    const float* NZ = (const float*)d_in[2];
    float* out = (float*)d_out;
    float* ws  = (float*)d_ws;   // needs 2*NBLK*NE*4 = 256 KiB

    router_kernel<<<dim3(NBLK), dim3(256), 0, stream>>>(H, W, NZ, out, ws);
    finalize_kernel<<<dim3(1), dim3(256), 0, stream>>>(ws, out);
}

// Round 11
// 263.874 us; speedup vs baseline: 1.1390x; 1.1390x over previous
//
#include <hip/hip_runtime.h>
#include <math.h>

#define BATCH 16384
#define DM    2048
#define NE    64
#define BT    32
#define DKC   128            // d-chunk staged per iteration
#define NBLK  (BATCH / BT)   // 512

// out layout (floats): idx @0 (32768), w @32768 (32768), logits @65536 (1048576), aux @1114112
#define OFF_W   32768
#define OFF_LG  65536
#define OFF_AUX 1114112

// ws layout (floats): probs partial [NBLK][64] @0, usage partial [NBLK][64] @32768. 256 KiB total.
#define WS_USAGE (NBLK * NE)

#define HS_S 36   // hs row stride (words): 16B-aligned, 4-way write conflict max
#define WS_S 68   // wsm row stride (words): 16B-aligned

__global__ __launch_bounds__(256) void router_kernel(
    const float* __restrict__ H, const float* __restrict__ W,
    const float* __restrict__ NZ, float* __restrict__ out,
    float* __restrict__ ws)
{
    __shared__ float hs  [DKC * HS_S];  // [d][t]  18432 B
    __shared__ float wsm [DKC * WS_S];  // [d][e]  34816 B
    __shared__ float lred[BT * 68];     // [t][e]  K-reduced logits, 8704 B
    __shared__ float ps  [16 * 68];     // epilogue prob partials, 4352 B
    __shared__ int   cnt [NE];          // usage counts

    const int tid  = threadIdx.x;
    const int blk  = blockIdx.x;
    const int kg   = tid >> 6;          // K-group (wave) 0..3
    const int lane = tid & 63;
    const int eg   = lane & 7;          // expert group -> e8..e8+7
    const int tg   = lane >> 3;         // token group  -> t4..t4+3
    const int e8   = eg << 3;
    const int t4g  = tg << 2;

    float acc[4][8];
    #pragma unroll
    for (int i = 0; i < 4; ++i)
        #pragma unroll
        for (int j = 0; j < 8; ++j) acc[i][j] = 0.f;

    const float* hb = H + (size_t)blk * BT * DM;

    for (int c = 0; c < DM / DKC; ++c) {
        const int D0 = c * DKC;
        // stage h tile [32 t][128 d] -> hs[d][t]; 4 float4/thread, d-minor-8 lane map
        #pragma unroll
        for (int p = 0; p < 4; ++p) {
            int f  = p * 256 + tid;            // 0..1023
            int t  = (f >> 3) & 31;
            int d4 = ((f >> 8) << 5) + ((f & 7) << 2);
            float4 v = *(const float4*)(hb + (size_t)t * DM + D0 + d4);
            hs[(d4+0)*HS_S + t] = v.x;
            hs[(d4+1)*HS_S + t] = v.y;
            hs[(d4+2)*HS_S + t] = v.z;
            hs[(d4+3)*HS_S + t] = v.w;
        }
        // stage W tile [64 e][128 d] -> wsm[d][e]; 8 float4/thread
        #pragma unroll
        for (int p = 0; p < 8; ++p) {
            int f  = p * 256 + tid;            // 0..2047
            int e  = (f >> 3) & 63;
            int d4 = ((f >> 9) << 5) + ((f & 7) << 2);
            float4 v = *(const float4*)(W + (size_t)e * DM + D0 + d4);
            wsm[(d4+0)*WS_S + e] = v.x;
            wsm[(d4+1)*WS_S + e] = v.y;
            wsm[(d4+2)*WS_S + e] = v.z;
            wsm[(d4+3)*WS_S + e] = v.w;
        }
        __syncthreads();
        // each wave computes its 32-d quarter of this chunk
        #pragma unroll 8
        for (int dd = 0; dd < 32; ++dd) {
            const int d = (kg << 5) + dd;
            const float4 a  = *(const float4*)(hs  + d*HS_S + t4g);
            const float4 b0 = *(const float4*)(wsm + d*WS_S + e8);
            const float4 b1 = *(const float4*)(wsm + d*WS_S + e8 + 4);
            const float av[4] = {a.x, a.y, a.z, a.w};
            const float bv[8] = {b0.x,b0.y,b0.z,b0.w,b1.x,b1.y,b1.z,b1.w};
            #pragma unroll
            for (int i = 0; i < 4; ++i)
                #pragma unroll
                for (int j = 0; j < 8; ++j)
                    acc[i][j] += av[i] * bv[j];
        }
        __syncthreads();
    }

    // deterministic K-reduction into lred (barriered, fixed order)
    #pragma unroll
    for (int g = 0; g < 4; ++g) {
        if (kg == g) {
            #pragma unroll
            for (int i = 0; i < 4; ++i) {
                float* row = lred + (t4g + i) * 68 + e8;
                if (g == 0) {
                    #pragma unroll
                    for (int j = 0; j < 8; ++j) row[j] = acc[i][j];
                } else {
                    #pragma unroll
                    for (int j = 0; j < 8; ++j) row[j] += acc[i][j];
                }
            }
        }
        __syncthreads();
    }

    // ---- proven epilogue (round-1), sourcing logits from lred ----
    const int er = tid & 15;
    const int tr = tid >> 4;
    const int e4 = er << 2;
    const int t2 = tr << 1;

    float l[2][4];
    {
        size_t tg0 = (size_t)blk * BT + t2;
        float4 n0 = *(const float4*)(NZ + tg0 * NE + e4);
        float4 n1 = *(const float4*)(NZ + (tg0 + 1) * NE + e4);
        float4 a0 = *(const float4*)(lred + (t2+0)*68 + e4);
        float4 a1 = *(const float4*)(lred + (t2+1)*68 + e4);
        l[0][0] = a0.x + n0.x*0.1f; l[0][1] = a0.y + n0.y*0.1f;
        l[0][2] = a0.z + n0.z*0.1f; l[0][3] = a0.w + n0.w*0.1f;
        l[1][0] = a1.x + n1.x*0.1f; l[1][1] = a1.y + n1.y*0.1f;
        l[1][2] = a1.z + n1.z*0.1f; l[1][3] = a1.w + n1.w*0.1f;
        *(float4*)(out + OFF_LG + tg0 * NE + e4)       = make_float4(l[0][0],l[0][1],l[0][2],l[0][3]);
        *(float4*)(out + OFF_LG + (tg0 + 1) * NE + e4) = make_float4(l[1][0],l[1][1],l[1][2],l[1][3]);
    }
    if (tid < NE) cnt[tid] = 0;
    __syncthreads();

    float pe0 = 0.f, pe1 = 0.f, pe2 = 0.f, pe3 = 0.f;
    #pragma unroll
    for (int i = 0; i < 2; ++i) {
        // local top-2 over this lane's 4 experts (stable: lower index wins ties)
        float m1 = l[i][0]; int i1 = e4;
        float m2 = -INFINITY; int i2 = NE;
        #pragma unroll
        for (int j = 1; j < 4; ++j) {
            float v = l[i][j]; int e = e4 + j;
            if (v > m1) { m2 = m1; i2 = i1; m1 = v; i1 = e; }
            else if (v > m2) { m2 = v; i2 = e; }
        }
        // butterfly merge across the 16 lanes of this token group
        #pragma unroll
        for (int mask = 1; mask < 16; mask <<= 1) {
            float om1 = __shfl_xor(m1, mask);
            int   oi1 = __shfl_xor(i1, mask);
            float om2 = __shfl_xor(m2, mask);
            int   oi2 = __shfl_xor(i2, mask);
            bool oFirst = (om1 > m1) || (om1 == m1 && oi1 < i1);
            if (oFirst) {
                bool selfSecond = (m1 > om2) || (m1 == om2 && i1 < oi2);
                m2 = selfSecond ? m1 : om2;
                i2 = selfSecond ? i1 : oi2;
                m1 = om1; i1 = oi1;
            } else {
                bool otherSecond = (om1 > m2) || (om1 == m2 && oi1 < i2);
                if (otherSecond) { m2 = om1; i2 = oi1; }
            }
        }
        // full-row softmax denom (m1 is the exact row max)
        float p0 = expf(l[i][0] - m1);
        float p1 = expf(l[i][1] - m1);
        float p2 = expf(l[i][2] - m1);
        float p3 = expf(l[i][3] - m1);
        float s = p0 + p1 + p2 + p3;
        #pragma unroll
        for (int mask = 1; mask < 16; mask <<= 1) s += __shfl_xor(s, mask);
        float inv = 1.0f / s;
        pe0 += p0*inv; pe1 += p1*inv; pe2 += p2*inv; pe3 += p3*inv;
        if (er == 0) {
            size_t tgi = (size_t)blk * BT + t2 + i;
            out[tgi*2 + 0] = (float)i1;
            out[tgi*2 + 1] = (float)i2;
            float x   = expf(m2 - m1);
            float w1v = 1.0f / (1.0f + x);
            out[OFF_W + tgi*2 + 0] = w1v;
            out[OFF_W + tgi*2 + 1] = x * w1v;
            atomicAdd(&cnt[i1], 1);
            atomicAdd(&cnt[i2], 1);
        }
    }
    ps[tr*68 + e4 + 0] = pe0;
    ps[tr*68 + e4 + 1] = pe1;
    ps[tr*68 + e4 + 2] = pe2;
    ps[tr*68 + e4 + 3] = pe3;
    __syncthreads();

    if (tid < NE) {
        float s = 0.f;
        #pragma unroll
        for (int r = 0; r < 16; ++r) s += ps[r*68 + tid];
        ws[(size_t)blk * NE + tid] = s;                          // prob partial
        ws[WS_USAGE + (size_t)blk * NE + tid] = (float)cnt[tid]; // usage partial
    }
}

__global__ __launch_bounds__(256) void finalize_kernel(
    const float* __restrict__ ws, float* __restrict__ out)
{
    __shared__ float psum[256];
    __shared__ float usum[256];
    const int tid  = threadIdx.x;
    const int e    = tid & 63;
    const int part = tid >> 6;   // 0..3, each covers 128 blocks in fixed order
    float p = 0.f, u = 0.f;
    for (int b = part * 128; b < part * 128 + 128; ++b) {
        p += ws[(size_t)b * NE + e];
        u += ws[WS_USAGE + (size_t)b * NE + e];
    }
    psum[part*64 + e] = p;
    usum[part*64 + e] = u;
    __syncthreads();
    if (tid < 64) {
        float pv = psum[tid] + psum[64+tid] + psum[128+tid] + psum[192+tid];
        float uv = usum[tid] + usum[64+tid] + usum[128+tid] + usum[192+tid];
        float v = (uv / (float)(BATCH * 2)) * (pv / (float)BATCH);
        #pragma unroll
        for (int mask = 1; mask < 64; mask <<= 1) v += __shfl_xor(v, mask);
        if (tid == 0) out[OFF_AUX] = v * ((float)NE * 0.001f);
    }
}

extern "C" void kernel_launch(void* const* d_in, const int* in_sizes, int n_in,
                              void* d_out, int out_size, void* d_ws, size_t ws_size,
                              hipStream_t stream)
{
    const float* H  = (const float*)d_in[0];
    const float* W  = (const float*)d_in[1];
    const float* NZ = (const float*)d_in[2];
    float* out = (float*)d_out;
    float* ws  = (float*)d_ws;   // needs 2*NBLK*NE*4 = 256 KiB

    router_kernel<<<dim3(NBLK), dim3(256), 0, stream>>>(H, W, NZ, out, ws);
    finalize_kernel<<<dim3(1), dim3(256), 0, stream>>>(ws, out);
}